// Round 14
// baseline (110.682 us; speedup 1.0000x reference)
//
#include <hip/hip_runtime.h>
#include <math.h>

// ConvCapsuleLayer fused: MFMA single-fp16 conv + register-resident routing.
// R14: R12 base (stride 976 — R13's "fix" was based on wrong bank math and
// made conflicts worse) + the REAL conflict fix: R7's 16-row vt transpose
// read (vt[t*16+((rb^(t&3))<<2)]) puts 16 lanes on each of only 4 start
// banks -> 2x conflict on all 32 transpose reads (R6 with 32-row vt: 4.39M
// conflicts; R7 16-row: 6.49M). Restore the 32-row XOR-8 vt (2 passes,
// uniform 8 dwords/bank for both write and read) -> also halves barriers.
// LDS 32K(vt)+4K+4K = 40960 B = exactly 4 blocks/CU.
// Batch scramble (faithful to reference reshape): i_x = b'>>1, b_x=((b'&1)<<3)+i.

typedef __attribute__((ext_vector_type(8))) _Float16 half8;
typedef __attribute__((ext_vector_type(4))) _Float16 half4;
typedef __attribute__((ext_vector_type(4))) float f32x4;

// W [400][256] fp32 -> Bh [52 kgroups][256 n][8 k] fp16, k padded 400->416.
__global__ void prep_w(const float* __restrict__ wg, _Float16* __restrict__ bh) {
    int k = blockIdx.x;        // 0..415
    int n = threadIdx.x;       // 0..255
    float f = (k < 400) ? wg[k * 256 + n] : 0.0f;
    bh[(k >> 3) * 2048 + n * 8 + (k & 7)] = (_Float16)f;
}

// DPP helpers: 0xB1 = quad_perm xor1, 0x4E = xor2, 0x124 = row_ror:4,
// 0x128 = row_ror:8 (== xor8 on the 16-lane ring).
template<int CTRL>
__device__ __forceinline__ float dppf(float x) {
    return __int_as_float(__builtin_amdgcn_update_dpp(
        0, __float_as_int(x), CTRL, 0xF, 0xF, true));
}
__device__ __forceinline__ float sum16(float x) {
    x += dppf<0xB1>(x);
    x += dppf<0x4E>(x);
    x += dppf<0x124>(x);
    x += dppf<0x128>(x);
    return x;
}

__global__ __launch_bounds__(256, 4) void caps_mfma_kernel(
    const float* __restrict__ xg,        // [16,32,32,8,16]
    const _Float16* __restrict__ bhg,    // [52][256][8]
    const float* __restrict__ bg,        // [256]
    float* __restrict__ outg)            // [16,32,32,16,16]
{
    __shared__ __align__(16) char buf[32768];  // xs (15616 B) / vt (32768 B)
    __shared__ float logit_s[1024];            // [q8][i8][o16]
    __shared__ float route_s[1024];            // [q8][o16][i8] (transposed)

    _Float16* xs = (_Float16*)buf;             // [i8][rc 61][c16], stride 976
    float*    vt = (float*)buf;                // votes^T [n256][r32], XOR-8

    const int t      = threadIdx.x;
    const int blk    = blockIdx.x;             // 2048
    const int wt     = blk & 3;
    const int h0     = (blk >> 2) & 31;
    const int bp     = blk >> 7;
    const int w0base = wt << 3;
    const int i_x    = bp >> 1;
    const int bbase  = (bp & 1) << 3;

    const float bias_r = bg[t];

    // ---- stage x window (60 rc x 16 c x 8 i = 7680 floats) as 1920 float4
    const float4* x4 = (const float4*)xg;
    #pragma unroll
    for (int kk = 0; kk < 8; ++kk) {
        int idx4 = t + (kk << 8);
        if (idx4 < 1920) {
            int c2 = idx4 & 3;                 // c = c2*4
            int i  = (idx4 >> 2) & 7;
            int rc = idx4 >> 5;                // 0..59 = r*12 + cc
            int r  = rc / 12;
            int cc = rc - r * 12;
            int hh = h0 + r - 2;
            int ww = w0base + cc - 2;
            float4 f = make_float4(0.f, 0.f, 0.f, 0.f);
            if (hh >= 0 && hh < 32 && ww >= 0 && ww < 32)
                f = x4[((((bbase + i) * 32 + hh) * 32 + ww) * 8 + i_x) * 4 + c2];
            half4 h4;
            h4.x = (_Float16)f.x; h4.y = (_Float16)f.y;
            h4.z = (_Float16)f.z; h4.w = (_Float16)f.w;
            *(half4*)&xs[i * 976 + rc * 16 + c2 * 4] = h4;
        }
    }
    __syncthreads();

    // ---- MFMA conv (unpipelined chunk loop, R7 style)
    const int wv   = t >> 6;
    const int lane = t & 63;
    const int lrow = lane & 15;     // m (and n) index within 16-tile
    const int h8   = lane >> 4;     // k-quarter 0..3
    const int ia   = lrow & 7;      // i of this A row
    const int qh   = lrow >> 3;     // q parity

    f32x4 acc[4][4];
    #pragma unroll
    for (int ms = 0; ms < 4; ++ms)
        #pragma unroll
        for (int nt = 0; nt < 4; ++nt)
            acc[ms][nt] = (f32x4){0.f, 0.f, 0.f, 0.f};

    const half8* bhp = (const half8*)bhg;   // [52][256] half8

#define CONV_CHUNK(CH, TAIL)                                                   \
    {                                                                          \
        int k0 = (CH) * 32 + h8 * 8;                                           \
        int p  = k0 >> 4;                                                      \
        int kh = p / 5;                                                        \
        int kw = p - kh * 5;                                                   \
        int abase = ia * 976 + (kh * 12 + kw + qh) * 16 + (k0 & 15);           \
        int g = (CH) * 4 + h8;                                                 \
        half8 bhv[4];                                                          \
        _Pragma("unroll")                                                      \
        for (int nt = 0; nt < 4; ++nt)                                         \
            bhv[nt] = bhp[g * 256 + wv * 64 + nt * 16 + lrow];                 \
        _Pragma("unroll")                                                      \
        for (int ms = 0; ms < 4; ++ms) {                                       \
            half8 ahv;                                                         \
            if (!(TAIL) || h8 < 2) ahv = *(const half8*)&xs[abase + ms * 32];  \
            else                   ahv = (half8)(_Float16)0.f;                 \
            _Pragma("unroll")                                                  \
            for (int nt = 0; nt < 4; ++nt)                                     \
                acc[ms][nt] = __builtin_amdgcn_mfma_f32_16x16x32_f16(          \
                    ahv, bhv[nt], acc[ms][nt], 0, 0, 0);                       \
        }                                                                      \
    }

    #pragma unroll
    for (int ch = 0; ch < 12; ++ch) CONV_CHUNK(ch, false)
    CONV_CHUNK(12, true)
#undef CONV_CHUNK

    // ---- transpose acc -> v[q][i] regs, 2 passes of 32 rows via 32 KB vt.
    // vt dword addr = n*32 + ((rb ^ (n&7))<<2), rb = r>>2 in 0..7.
    // Write: 8 starts x 8 lanes; read: 8 starts x 8 lanes -> both 8 dw/bank.
    float v[8][8];
    #pragma unroll
    for (int pass = 0; pass < 2; ++pass) {
        __syncthreads();                       // xs / previous-pass reads done
        #pragma unroll
        for (int msp = 0; msp < 2; ++msp) {
            int rb = msp * 4 + h8;
            #pragma unroll
            for (int nt = 0; nt < 4; ++nt) {
                int n = wv * 64 + nt * 16 + lrow;
                *(f32x4*)&vt[n * 32 + ((rb ^ (n & 7)) << 2)] =
                    acc[pass * 2 + msp][nt];
            }
        }
        __syncthreads();
        #pragma unroll
        for (int rb = 0; rb < 8; ++rb) {
            f32x4 x = *(const f32x4*)&vt[t * 32 + ((rb ^ (t & 7)) << 2)];
            int q  = pass * 4 + (rb >> 1);
            int ib = (rb & 1) * 4;
            v[q][ib + 0] = x[0];
            v[q][ib + 1] = x[1];
            v[q][ib + 2] = x[2];
            v[q][ib + 3] = x[3];
        }
    }

    // ---- routing from registers: thread t owns od=t (o=t>>4, d=t&15).
    const int o = t >> 4;
    const int d = t & 15;
    const bool b8  = (d & 8) != 0;
    const bool b2v = (d & 2) != 0;
    const bool b1v = (d & 1) != 0;
    const int  im  = (b8 ? 4 : 0) + (b2v ? 2 : 0) + (b1v ? 1 : 0);
    const bool wr  = (d & 4) == 0;
    float act_r[8];

    // agreement: 8 dot-sums over 16 lanes; DPP reduce-scatter, one ds_swizzle
    auto agree = [&](const float* vq, float act, int q, bool first) {
        float p[8];
        #pragma unroll
        for (int i = 0; i < 8; ++i) p[i] = vq[i] * act;
        float s4[4];
        #pragma unroll
        for (int j = 0; j < 4; ++j) {          // exchange lane^8 (ror8)
            float send = b8 ? p[j] : p[j + 4];
            float rcv  = dppf<0x128>(send);
            s4[j] = (b8 ? p[j + 4] : p[j]) + rcv;
        }
        float s2[2];
        #pragma unroll
        for (int j = 0; j < 2; ++j) {          // exchange lane^2
            float send = b2v ? s4[j] : s4[j + 2];
            float rcv  = dppf<0x4E>(send);
            s2[j] = (b2v ? s4[j + 2] : s4[j]) + rcv;
        }
        float send = b1v ? s2[0] : s2[1];      // exchange lane^1
        float rcv  = dppf<0xB1>(send);
        float s1 = (b1v ? s2[1] : s2[0]) + rcv;
        // final: exchange lane^4 (the one non-DPP involution) via ds_swizzle
        float L = s1 + __int_as_float(
            __builtin_amdgcn_ds_swizzle(__float_as_int(s1), 0x101F));
        if (wr) {
            float* dst = &logit_s[q * 128 + im * 16 + o];
            if (first) *dst = L; else *dst += L;
        }
    };

    // ---- it = 0: route == 1/16 exactly; logits written with '=' (no init).
    #pragma unroll
    for (int q = 0; q < 8; ++q) {
        float s = 0.0f;
        #pragma unroll
        for (int i = 0; i < 8; ++i) s += v[q][i];
        float pre = bias_r + 0.0625f * s;
        float n2 = sum16(pre * pre);
        float act = pre * sqrtf(n2) * __builtin_amdgcn_rcpf(1.0f + n2);
        act_r[q] = act;
        agree(v[q], act, q, true);
    }
    __syncthreads();

    // ---- it = 1, 2
    #pragma unroll
    for (int it = 1; it < 3; ++it) {
        {   // parallel softmax: thread -> row r = t>>2 (q=r>>3,i=r&7), 4 o's
            int rr = t >> 2, sq = rr >> 3, si = rr & 7, sj = t & 3;
            f32x4 lg = *(const f32x4*)&logit_s[rr * 16 + sj * 4];
            float m = fmaxf(fmaxf(lg[0], lg[1]), fmaxf(lg[2], lg[3]));
            m = fmaxf(m, dppf<0xB1>(m));       // quad max (4 lanes = same row)
            m = fmaxf(m, dppf<0x4E>(m));
            float e0 = __expf(lg[0] - m), e1 = __expf(lg[1] - m);
            float e2 = __expf(lg[2] - m), e3 = __expf(lg[3] - m);
            float ss = e0 + e1 + e2 + e3;
            ss += dppf<0xB1>(ss);
            ss += dppf<0x4E>(ss);
            float inv = __builtin_amdgcn_rcpf(ss);
            float* rt = &route_s[sq * 128 + si];
            rt[(sj * 4 + 0) * 8] = e0 * inv;
            rt[(sj * 4 + 1) * 8] = e1 * inv;
            rt[(sj * 4 + 2) * 8] = e2 * inv;
            rt[(sj * 4 + 3) * 8] = e3 * inv;
        }
        __syncthreads();

        #pragma unroll
        for (int q = 0; q < 8; ++q) {
            const f32x4* rp = (const f32x4*)&route_s[q * 128 + o * 8];
            f32x4 ra = rp[0], rb2 = rp[1];
            float pre = bias_r
                + ra[0] * v[q][0] + ra[1] * v[q][1] + ra[2] * v[q][2] + ra[3] * v[q][3]
                + rb2[0] * v[q][4] + rb2[1] * v[q][5] + rb2[2] * v[q][6] + rb2[3] * v[q][7];
            float n2 = sum16(pre * pre);
            float act = pre * sqrtf(n2) * __builtin_amdgcn_rcpf(1.0f + n2);
            act_r[q] = act;
            if (it == 1) agree(v[q], act, q, false);
        }
        if (it == 1) __syncthreads();
    }

    // ---- output [b',h0,w0base+q,o,d]
    #pragma unroll
    for (int q = 0; q < 8; ++q)
        outg[((bp * 32 + h0) * 32 + (w0base + q)) * 256 + t] = act_r[q];
}

extern "C" void kernel_launch(void* const* d_in, const int* in_sizes, int n_in,
                              void* d_out, int out_size, void* d_ws, size_t ws_size,
                              hipStream_t stream) {
    const float* x = (const float*)d_in[0];
    const float* w = (const float*)d_in[1];
    const float* b = (const float*)d_in[2];
    float* out = (float*)d_out;

    _Float16* bh = (_Float16*)d_ws;            // 52*256*8*2 = 106496 B

    hipLaunchKernelGGL(prep_w, dim3(416), dim3(256), 0, stream, w, bh);
    hipLaunchKernelGGL(caps_mfma_kernel, dim3(2048), dim3(256), 0, stream,
                       x, bh, b, out);
}